// Round 9
// baseline (257.312 us; speedup 1.0000x reference)
//
#include <hip/hip_runtime.h>
#include <math.h>

// BaseHybridHead, 2 stream-ordered kernels:
//  KA: pre-GEMM + rank-1 expand -> psi0F (fragment-major, 16MB); Arm rows ->
//      Armf (fragment-major, 2MB); zero z[8192][10] + cnt[16]
//  KB: GEMM psif = psi0 @ Arm^T with B-tile resident in LDS (64 cols x K,
//      two 64KB K-phases, 3 barriers TOTAL), A-frags loaded as contiguous 1KB
//      global reads from psi0F (no gather, no A staging). Fused +-square
//      measurement epilogue -> atomicAdd z; last nt block per M-slice applies
//      the post head (atomic-counter idiom, verified R7/R8).
//
// Fragment-major layout (both psi0F and Armf):
//   element A[row][k] stored at f16-index
//     (row>>4)*16384 + (k>>5)*512 + ((row&15) + 16*((k>>3)&3))*8 + (k&7)
//   so frag for (tile, kchunk) = contiguous 1KB, lane-linear = MFMA operand order.

#define NQ   10
#define NREG 16
#define DIM  1024

typedef _Float16 f16;
typedef _Float16 f16x8 __attribute__((ext_vector_type(8)));
typedef float    f32x4 __attribute__((ext_vector_type(4)));

// ---------------------------------------------------------------- gate ops
template<int BB>
__device__ __forceinline__ void ry_lane(float (&s)[NREG], int lane, float c, float si) {
    float sgn = ((lane >> BB) & 1) ? si : -si;
    #pragma unroll
    for (int r = 0; r < NREG; ++r) {
        float o = __shfl_xor(s[r], 1 << BB);
        s[r] = fmaf(sgn, o, c * s[r]);
    }
}
template<int P>
__device__ __forceinline__ void ry_reg(float (&s)[NREG], float c, float si) {
    const int m = 1 << P;
    #pragma unroll
    for (int r = 0; r < NREG; ++r) {
        if ((r & m) == 0) {
            float a = s[r], b = s[r + m];
            s[r]     = fmaf(c, a, -si * b);
            s[r + m] = fmaf(si, a,  c * b);
        }
    }
}
__device__ __forceinline__ void cnot_5_6(float (&s)[NREG], int lane) {
    bool sel = (lane & 1) != 0;
    #pragma unroll
    for (int r = 0; r < 8; ++r) {
        float a = s[r], b = s[r + 8];
        s[r]     = sel ? b : a;
        s[r + 8] = sel ? a : b;
    }
}
template<int PC, int PT>
__device__ __forceinline__ void cnot_reg(float (&s)[NREG]) {
    #pragma unroll
    for (int r = 0; r < NREG; ++r) {
        if (((r >> PC) & 1) && !((r >> PT) & 1)) {
            float t = s[r];
            s[r] = s[r ^ (1 << PT)];
            s[r ^ (1 << PT)] = t;
        }
    }
}
__device__ __forceinline__ void perm_even(float (&s)[NREG], int lane) {
    int src = lane ^ (((((lane >> 5) & 1) << 4)) | ((((lane >> 3) & 1) << 2)) | (((lane >> 1) & 1)));
    #pragma unroll
    for (int r = 0; r < NREG; ++r) s[r] = __shfl(s[r], src);
}
__device__ __forceinline__ void perm_odd(float (&s)[NREG], int lane) {
    int src = lane ^ (((((lane >> 4) & 1) << 3)) | ((((lane >> 2) & 1) << 1)));
    #pragma unroll
    for (int r = 0; r < NREG; ++r) s[r] = __shfl(s[r], src);
}

#define APPLY_RY_ALL(CARR, SARR, BASE)                                        \
    { float c_, s_;                                                           \
      c_=__shfl(CARR,(BASE)+0); s_=__shfl(SARR,(BASE)+0); ry_lane<5>(s,lane,c_,s_); \
      c_=__shfl(CARR,(BASE)+1); s_=__shfl(SARR,(BASE)+1); ry_lane<4>(s,lane,c_,s_); \
      c_=__shfl(CARR,(BASE)+2); s_=__shfl(SARR,(BASE)+2); ry_lane<3>(s,lane,c_,s_); \
      c_=__shfl(CARR,(BASE)+3); s_=__shfl(SARR,(BASE)+3); ry_lane<2>(s,lane,c_,s_); \
      c_=__shfl(CARR,(BASE)+4); s_=__shfl(SARR,(BASE)+4); ry_lane<1>(s,lane,c_,s_); \
      c_=__shfl(CARR,(BASE)+5); s_=__shfl(SARR,(BASE)+5); ry_lane<0>(s,lane,c_,s_); \
      c_=__shfl(CARR,(BASE)+6); s_=__shfl(SARR,(BASE)+6); ry_reg<3>(s,c_,s_);       \
      c_=__shfl(CARR,(BASE)+7); s_=__shfl(SARR,(BASE)+7); ry_reg<2>(s,c_,s_);       \
      c_=__shfl(CARR,(BASE)+8); s_=__shfl(SARR,(BASE)+8); ry_reg<1>(s,c_,s_);       \
      c_=__shfl(CARR,(BASE)+9); s_=__shfl(SARR,(BASE)+9); ry_reg<0>(s,c_,s_); }

__device__ __forceinline__ void async16(const void* g, void* l) {
    __builtin_amdgcn_global_load_lds(
        (const __attribute__((address_space(1))) void*)g,
        (__attribute__((address_space(3))) void*)l, 16, 0, 0);
}

// write one row (1024 f16 held as wave registers) in fragment-major order.
// source: lane holds e = lane*16 + r, v0 = r 0..7, v1 = r 8..15.
__device__ __forceinline__ void store_frag_major(
    f16* base, int row, int lane, float4 v0, float4 v1)
{
    size_t idx0 = (size_t)(row >> 4) * 16384 + (size_t)(lane >> 1) * 512
                + (size_t)((row & 15) + ((lane & 1) * 2) * 16) * 8;
    *(float4*)((char*)base + idx0 * 2)       = v0;   // k-granule q
    *(float4*)((char*)base + idx0 * 2 + 256) = v1;   // k-granule q+1 (+128 f16)
}

// ---------------------------------------------------------------- KA
// grid 2048 x 256: one sample per wave; blocks 0..511 also build 2 Arm rows each.
__global__ __launch_bounds__(256) void ka_prepare(
    const float* __restrict__ X, const float* __restrict__ Wpre,
    const float* __restrict__ bpre, const float* __restrict__ qp,
    f16* __restrict__ psi0F, f16* __restrict__ Armf, float* __restrict__ z,
    int* __restrict__ cnt, int B)
{
    const int tid = threadIdx.x, lane = tid & 63, wv = tid >> 6;

    // ---- zero z accumulator + tile counters
    {
        int idx = blockIdx.x * 256 + tid;
        if (idx < 8192 * NQ) z[idx] = 0.0f;
        else if (idx < 8192 * NQ + 16) cnt[idx - 8192 * NQ] = 0;
    }

    // ---- psi0: one sample per wave
    {
        int sample = blockIdx.x * 4 + wv;
        if (sample < B) {
            const float* xrow = X + (size_t)sample * 512;
            float4 x0 = ((const float4*)xrow)[lane];
            float4 x1 = ((const float4*)xrow)[64 + lane];
            float acc[NQ];
            #pragma unroll
            for (int q = 0; q < NQ; ++q) {
                const float* wr = Wpre + q * 512;
                float4 w0 = ((const float4*)wr)[lane];
                float4 w1 = ((const float4*)wr)[64 + lane];
                float a = x0.x * w0.x;
                a = fmaf(x0.y, w0.y, a); a = fmaf(x0.z, w0.z, a); a = fmaf(x0.w, w0.w, a);
                a = fmaf(x1.x, w1.x, a); a = fmaf(x1.y, w1.y, a);
                a = fmaf(x1.z, w1.z, a); a = fmaf(x1.w, w1.w, a);
                acc[q] = a;
            }
            #pragma unroll
            for (int q = 0; q < NQ; ++q) {
                float v = acc[q];
                #pragma unroll
                for (int d = 32; d >= 1; d >>= 1) v += __shfl_xor(v, d);
                acc[q] = v;
            }
            float pre = acc[0];
            #pragma unroll
            for (int q = 1; q < NQ; ++q) pre = (lane == q) ? acc[q] : pre;
            float c45 = 0.0f, s45 = 0.0f;
            if (lane < NQ) {
                float th = tanhf(pre + bpre[lane]) * 1.5707963267948966f;
                sincosf(0.5f * th + 0.7853981633974483f, &s45, &c45);
            }
            float lv = 1.0f;
            #pragma unroll
            for (int w = 0; w < 6; ++w) {
                float f0 = __shfl(c45, w), f1 = __shfl(s45, w);
                lv *= ((lane >> (5 - w)) & 1) ? f1 : f0;
            }
            float c6 = __shfl(c45, 6), s6 = __shfl(s45, 6);
            float c7 = __shfl(c45, 7), s7 = __shfl(s45, 7);
            float c8 = __shfl(c45, 8), s8 = __shfl(s45, 8);
            float c9 = __shfl(c45, 9), s9 = __shfl(s45, 9);
            float g01[4] = {c6 * c7, c6 * s7, s6 * c7, s6 * s7};
            float g23[4] = {c8 * c9, c8 * s9, s8 * c9, s8 * s9};
            union { f16 h[16]; float4 v[2]; } u;
            #pragma unroll
            for (int r = 0; r < NREG; ++r)
                u.h[r] = (f16)(lv * g01[r >> 2] * g23[r & 3]);
            store_frag_major(psi0F, sample, lane, u.v[0], u.v[1]);
        }
    }

    // ---- Arm rows: blocks 0..511, waves 0,1 build row (blockIdx*2 + wv)
    if (wv < 2) {
        int row = blockIdx.x * 2 + wv;
        if (row < DIM) {
            float cw = 1.0f, swn = 0.0f;
            if (lane < 60) {
                float s_, c_;
                sincosf(0.5f * qp[10 + lane], &s_, &c_);
                cw = c_; swn = -s_;
            }
            float s[NREG];
            int srcLane = row >> 4, srcReg = row & 15;
            #pragma unroll
            for (int r = 0; r < NREG; ++r)
                s[r] = (lane == srcLane && r == srcReg) ? 1.0f : 0.0f;
            for (int kk = 6; kk >= 1; --kk) {
                APPLY_RY_ALL(cw, swn, (kk - 1) * 10);
                perm_odd(s, lane);
                cnot_5_6(s, lane);
                cnot_reg<2, 1>(s);
                perm_even(s, lane);
                cnot_reg<3, 2>(s);
                cnot_reg<1, 0>(s);
            }
            union { f16 h[16]; float4 v[2]; } u;
            #pragma unroll
            for (int r = 0; r < NREG; ++r) u.h[r] = (f16)s[r];
            store_frag_major(Armf, row, lane, u.v[0], u.v[1]);
        }
    }
}

// ---------------------------------------------------------------- KB
// 256 blocks x 512 threads (1 block/CU, 8 waves). Block = (ms = b&15, nt = b>>4):
// rows ms*512..+511, cols nt*64..+63. B tile in LDS (two 64KB K-phases).
// Wave wv: rows wv*64..+63 (4 m-subtiles), all 64 cols (4 n-frags).
__global__ __launch_bounds__(512, 1) void kb_gemm_measure(
    const f16* __restrict__ psi0F, const f16* __restrict__ Armf,
    const float* __restrict__ Wpost, const float* __restrict__ bpost,
    float* __restrict__ z, int* __restrict__ cnt, float* __restrict__ out)
{
    __shared__ __align__(16) char smem[65536];
    const int tid = threadIdx.x, lane = tid & 63, wv = tid >> 6;
    const int ms = blockIdx.x & 15, nt = blockIdx.x >> 4;

    f32x4 acc[4][4] = {};

    const char* aBase[4];
    #pragma unroll
    for (int i = 0; i < 4; ++i) {
        int mt = ms * 32 + wv * 4 + i;
        aBase[i] = (const char*)psi0F + (size_t)mt * 32768 + lane * 16;
    }
    const char* bGlob = (const char*)Armf + (size_t)nt * 4 * 32768;

    for (int p = 0; p < 2; ++p) {
        if (p) __syncthreads();  // protect LDS overwrite
        // stage B phase p: 4 nt16-slices x 16KB, lane-linear
        #pragma unroll
        for (int sl = 0; sl < 4; ++sl) {
            #pragma unroll
            for (int rr = 0; rr < 2; ++rr) {
                int off = (rr * 512 + tid) * 16;
                async16(bGlob + sl * 32768 + p * 16384 + off, smem + sl * 16384 + off);
            }
        }
        __syncthreads();  // staging complete
        #pragma unroll 4
        for (int kl = 0; kl < 16; ++kl) {
            int kc = p * 16 + kl;
            f16x8 af[4], bf[4];
            #pragma unroll
            for (int i = 0; i < 4; ++i)
                af[i] = *(const f16x8*)(aBase[i] + kc * 1024);
            #pragma unroll
            for (int j = 0; j < 4; ++j)
                bf[j] = *(const f16x8*)(smem + j * 16384 + kl * 1024 + lane * 16);
            #pragma unroll
            for (int i = 0; i < 4; ++i)
                #pragma unroll
                for (int j = 0; j < 4; ++j)
                    acc[i][j] = __builtin_amdgcn_mfma_f32_16x16x32_f16(af[i], bf[j], acc[i][j], 0, 0, 0);
        }
    }

    // ---- fused +-square measurement epilogue ----
    // col n = nt*64 + j*16 + (lane&15): n[9:6]=nt, n[5:4]=j, n[3:0]=lane&15
    const float sg0 = (nt & 8) ? -1.0f : 1.0f;  // wire0 <- n[9]
    const float sg1 = (nt & 4) ? -1.0f : 1.0f;  // wire1 <- n[8]
    const float sg2 = (nt & 2) ? -1.0f : 1.0f;  // wire2 <- n[7]
    const float sg3 = (nt & 1) ? -1.0f : 1.0f;  // wire3 <- n[6]

    #pragma unroll
    for (int i = 0; i < 4; ++i) {
        #pragma unroll
        for (int t = 0; t < 4; ++t) {
            float p0 = acc[i][0][t] * acc[i][0][t];
            float p1 = acc[i][1][t] * acc[i][1][t];
            float p2 = acc[i][2][t] * acc[i][2][t];
            float p3 = acc[i][3][t] * acc[i][3][t];
            float t0  = (p0 + p1) + (p2 + p3);
            float tw5 = (p0 - p1) + (p2 - p3);  // wire5 <- n[4] = j&1
            float tw4 = (p0 + p1) - (p2 + p3);  // wire4 <- n[5] = j>>1
            // butterfly over lane bits 0..3 = n[0..3] -> wires 9,8,7,6
            float s1 = __shfl_xor(t0, 1);
            float Av = t0 + s1;
            float Bv = (lane & 1) ? s1 - t0 : t0 - s1;
            float sA = __shfl_xor(Av, 2), sB = __shfl_xor(Bv, 2);
            float AP = Av + sA;
            float AM = (lane & 2) ? sA - Av : Av - sA;
            float BP = Bv + sB;
            float sAP = __shfl_xor(AP, 4), sAM = __shfl_xor(AM, 4), sBP = __shfl_xor(BP, 4);
            float APP = AP + sAP;
            float APM = (lane & 4) ? sAP - AP : AP - sAP;
            float AMP = AM + sAM;
            float BPP = BP + sBP;
            float a1 = __shfl_xor(APP, 8), a2 = __shfl_xor(APM, 8);
            float a3 = __shfl_xor(AMP, 8), a4 = __shfl_xor(BPP, 8);
            float T0 = APP + a1;
            float S6 = (lane & 8) ? a1 - APP : APP - a1;
            float S7 = APM + a2;
            float S8 = AMP + a3;
            float S9 = BPP + a4;
            float T5 = tw5, T4 = tw4;
            T5 += __shfl_xor(T5, 1); T5 += __shfl_xor(T5, 2);
            T5 += __shfl_xor(T5, 4); T5 += __shfl_xor(T5, 8);
            T4 += __shfl_xor(T4, 1); T4 += __shfl_xor(T4, 2);
            T4 += __shfl_xor(T4, 4); T4 += __shfl_xor(T4, 8);
            if ((lane & 15) == 0) {
                int row = ms * 512 + wv * 64 + i * 16 + (lane >> 4) * 4 + t;
                float* d = &z[(size_t)row * 10];
                atomicAdd(d + 0, sg0 * T0);
                atomicAdd(d + 1, sg1 * T0);
                atomicAdd(d + 2, sg2 * T0);
                atomicAdd(d + 3, sg3 * T0);
                atomicAdd(d + 4, T4);
                atomicAdd(d + 5, T5);
                atomicAdd(d + 6, S6);
                atomicAdd(d + 7, S7);
                atomicAdd(d + 8, S8);
                atomicAdd(d + 9, S9);
            }
        }
    }

    // ---- last-block-per-M-slice finalize (verified R7/R8; now 16 contributors) ----
    __threadfence();
    __syncthreads();
    int* flag = (int*)smem;  // B tile no longer needed
    if (tid == 0) *flag = (atomicAdd(&cnt[ms], 1) == 15) ? 1 : 0;
    __syncthreads();
    if (*flag) {
        int r = tid;  // 512 rows, 512 threads
        float* zp = &z[((size_t)ms * 512 + r) * 10];
        float o0 = bpost[0], o1 = bpost[1];
        #pragma unroll
        for (int w = 0; w < NQ; ++w) {
            float zw = atomicAdd(&zp[w], 0.0f);  // coherent read
            o0 = fmaf(zw, Wpost[w], o0);
            o1 = fmaf(zw, Wpost[NQ + w], o1);
        }
        out[((size_t)ms * 512 + r) * 2 + 0] = o0;
        out[((size_t)ms * 512 + r) * 2 + 1] = o1;
    }
}

// ---------------------------------------------------------------- fallback (R1, verified)
template<int BC, int BT>
__device__ __forceinline__ void cnot_lane(float (&s)[NREG], int lane) {
    int src = ((lane >> BC) & 1) ? (lane ^ (1 << BT)) : lane;
    #pragma unroll
    for (int r = 0; r < NREG; ++r) s[r] = __shfl(s[r], src);
}

__global__ __launch_bounds__(256) void hybrid_head_fallback(
    const float* __restrict__ X, const float* __restrict__ Wpre,
    const float* __restrict__ bpre, const float* __restrict__ qp,
    const float* __restrict__ Wpost, const float* __restrict__ bpost,
    float* __restrict__ out, int B)
{
    const int lane = threadIdx.x & 63;
    const int wave = threadIdx.x >> 6;
    const int sample = blockIdx.x * 4 + wave;
    if (sample >= B) return;

    const float* xrow = X + (size_t)sample * 512;
    float4 x0 = ((const float4*)xrow)[lane];
    float4 x1 = ((const float4*)xrow)[64 + lane];
    float acc[NQ];
    #pragma unroll
    for (int q = 0; q < NQ; ++q) {
        const float* wr = Wpre + q * 512;
        float4 w0 = ((const float4*)wr)[lane];
        float4 w1 = ((const float4*)wr)[64 + lane];
        float a = x0.x * w0.x;
        a = fmaf(x0.y, w0.y, a); a = fmaf(x0.z, w0.z, a); a = fmaf(x0.w, w0.w, a);
        a = fmaf(x1.x, w1.x, a); a = fmaf(x1.y, w1.y, a);
        a = fmaf(x1.z, w1.z, a); a = fmaf(x1.w, w1.w, a);
        acc[q] = a;
    }
    #pragma unroll
    for (int q = 0; q < NQ; ++q) {
        float v = acc[q];
        #pragma unroll
        for (int d = 32; d >= 1; d >>= 1) v += __shfl_xor(v, d);
        acc[q] = v;
    }
    float pre = acc[0];
    #pragma unroll
    for (int q = 1; q < NQ; ++q) pre = (lane == q) ? acc[q] : pre;
    float cth = 1.0f, sth = 0.0f;
    if (lane < NQ) {
        float th = tanhf(pre + bpre[lane]) * 1.5707963267948966f;
        sincosf(0.5f * th, &sth, &cth);
    }
    float cw = 1.0f, sw = 0.0f;
    if (lane < 60) sincosf(0.5f * qp[10 + lane], &sw, &cw);

    float s[NREG];
    #pragma unroll
    for (int r = 0; r < NREG; ++r) s[r] = 0.03125f;
    APPLY_RY_ALL(cth, sth, 0);
    for (int k = 0; k < 6; ++k) {
        perm_even(s, lane);
        cnot_reg<3, 2>(s);
        cnot_reg<1, 0>(s);
        perm_odd(s, lane);
        cnot_5_6(s, lane);
        cnot_reg<2, 1>(s);
        APPLY_RY_ALL(cw, sw, k * 10);
    }
    float p[NREG], tot = 0.0f;
    #pragma unroll
    for (int r = 0; r < NREG; ++r) { p[r] = s[r] * s[r]; tot += p[r]; }
    float z[NQ];
    #pragma unroll
    for (int w = 0; w < 6; ++w) z[w] = ((lane >> (5 - w)) & 1) ? -tot : tot;
    z[6] = z[7] = z[8] = z[9] = 0.0f;
    #pragma unroll
    for (int r = 0; r < NREG; ++r) {
        z[6] += ((r >> 3) & 1) ? -p[r] : p[r];
        z[7] += ((r >> 2) & 1) ? -p[r] : p[r];
        z[8] += ((r >> 1) & 1) ? -p[r] : p[r];
        z[9] += ((r >> 0) & 1) ? -p[r] : p[r];
    }
    #pragma unroll
    for (int w = 0; w < NQ; ++w) {
        float v = z[w];
        #pragma unroll
        for (int d = 32; d >= 1; d >>= 1) v += __shfl_xor(v, d);
        z[w] = v;
    }
    if (lane < 2) {
        const float* wp = Wpost + lane * NQ;
        float o = bpost[lane];
        #pragma unroll
        for (int w = 0; w < NQ; ++w) o = fmaf(z[w], wp[w], o);
        out[(size_t)sample * 2 + lane] = o;
    }
}

// ---------------------------------------------------------------- launch
extern "C" void kernel_launch(void* const* d_in, const int* in_sizes, int n_in,
                              void* d_out, int out_size, void* d_ws, size_t ws_size,
                              hipStream_t stream) {
    const float* X     = (const float*)d_in[0];
    const float* Wpre  = (const float*)d_in[1];
    const float* bpre  = (const float*)d_in[2];
    const float* qp    = (const float*)d_in[3];
    const float* Wpost = (const float*)d_in[4];
    const float* bpost = (const float*)d_in[5];
    float* out = (float*)d_out;
    int B = in_sizes[0] / 512;  // 8192

    size_t psi0_b = (size_t)B * DIM * sizeof(f16);      // 16 MB
    size_t arm_b  = (size_t)DIM * DIM * sizeof(f16);    // 2 MB
    size_t z_b    = (size_t)B * NQ * sizeof(float);     // 320 KB
    size_t cnt_b  = 16 * sizeof(int);
    size_t need = psi0_b + arm_b + z_b + cnt_b;

    if (B != 8192 || ws_size < need) {
        hipLaunchKernelGGL(hybrid_head_fallback, dim3((B + 3) / 4), dim3(256), 0, stream,
                           X, Wpre, bpre, qp, Wpost, bpost, out, B);
        return;
    }

    char* ws = (char*)d_ws;
    f16*   psi0F = (f16*)ws;
    f16*   Armf  = (f16*)(ws + psi0_b);
    float* z     = (float*)(ws + psi0_b + arm_b);
    int*   cnt   = (int*)(ws + psi0_b + arm_b + z_b);

    hipLaunchKernelGGL(ka_prepare, dim3(2048), dim3(256), 0, stream,
                       X, Wpre, bpre, qp, psi0F, Armf, z, cnt, B);
    hipLaunchKernelGGL(kb_gemm_measure, dim3(256), dim3(512), 0, stream,
                       psi0F, Armf, Wpost, bpost, z, cnt, out);
}

// Round 10
// 239.949 us; speedup vs baseline: 1.0724x; 1.0724x over previous
//
#include <hip/hip_runtime.h>
#include <math.h>

// BaseHybridHead, 2 stream-ordered kernels:
//  KA: pre-GEMM + rank-1 expand -> psi0F (fragment-major, 16MB); Arm rows ->
//      Armf (fragment-major, 2MB); zero z[8192][10] + cnt[128]   [R9-verified]
//  KB: GEMM psif = psi0 @ Arm^T, 64x128 tile, BK=64, double-buffered LDS with
//      ONE barrier per iter; fragment-major staging = wave-linear global->LDS
//      (coalesced) and contiguous-1KB frag ds_read_b128 (conflict-free by
//      construction). Fused +-square measurement epilogue -> atomicAdd z
//      [R6-verified mapping]; last nB block per M-tile applies post head
//      [R7/R8-verified atomic-counter idiom].
//
// Fragment-major layout (psi0F and Armf), per R9:
//   A[row][k] at f16-index (row>>4)*16384 + (k>>5)*512
//                         + ((row&15) + 16*((k>>3)&3))*8 + (k&7)
//   => frag for (row-tile, k-chunk) = contiguous 1KB, lane-linear MFMA order.

#define NQ   10
#define NREG 16
#define DIM  1024

typedef _Float16 f16;
typedef _Float16 f16x8 __attribute__((ext_vector_type(8)));
typedef float    f32x4 __attribute__((ext_vector_type(4)));

// ---------------------------------------------------------------- gate ops
template<int BB>
__device__ __forceinline__ void ry_lane(float (&s)[NREG], int lane, float c, float si) {
    float sgn = ((lane >> BB) & 1) ? si : -si;
    #pragma unroll
    for (int r = 0; r < NREG; ++r) {
        float o = __shfl_xor(s[r], 1 << BB);
        s[r] = fmaf(sgn, o, c * s[r]);
    }
}
template<int P>
__device__ __forceinline__ void ry_reg(float (&s)[NREG], float c, float si) {
    const int m = 1 << P;
    #pragma unroll
    for (int r = 0; r < NREG; ++r) {
        if ((r & m) == 0) {
            float a = s[r], b = s[r + m];
            s[r]     = fmaf(c, a, -si * b);
            s[r + m] = fmaf(si, a,  c * b);
        }
    }
}
__device__ __forceinline__ void cnot_5_6(float (&s)[NREG], int lane) {
    bool sel = (lane & 1) != 0;
    #pragma unroll
    for (int r = 0; r < 8; ++r) {
        float a = s[r], b = s[r + 8];
        s[r]     = sel ? b : a;
        s[r + 8] = sel ? a : b;
    }
}
template<int PC, int PT>
__device__ __forceinline__ void cnot_reg(float (&s)[NREG]) {
    #pragma unroll
    for (int r = 0; r < NREG; ++r) {
        if (((r >> PC) & 1) && !((r >> PT) & 1)) {
            float t = s[r];
            s[r] = s[r ^ (1 << PT)];
            s[r ^ (1 << PT)] = t;
        }
    }
}
__device__ __forceinline__ void perm_even(float (&s)[NREG], int lane) {
    int src = lane ^ (((((lane >> 5) & 1) << 4)) | ((((lane >> 3) & 1) << 2)) | (((lane >> 1) & 1)));
    #pragma unroll
    for (int r = 0; r < NREG; ++r) s[r] = __shfl(s[r], src);
}
__device__ __forceinline__ void perm_odd(float (&s)[NREG], int lane) {
    int src = lane ^ (((((lane >> 4) & 1) << 3)) | ((((lane >> 2) & 1) << 1)));
    #pragma unroll
    for (int r = 0; r < NREG; ++r) s[r] = __shfl(s[r], src);
}

#define APPLY_RY_ALL(CARR, SARR, BASE)                                        \
    { float c_, s_;                                                           \
      c_=__shfl(CARR,(BASE)+0); s_=__shfl(SARR,(BASE)+0); ry_lane<5>(s,lane,c_,s_); \
      c_=__shfl(CARR,(BASE)+1); s_=__shfl(SARR,(BASE)+1); ry_lane<4>(s,lane,c_,s_); \
      c_=__shfl(CARR,(BASE)+2); s_=__shfl(SARR,(BASE)+2); ry_lane<3>(s,lane,c_,s_); \
      c_=__shfl(CARR,(BASE)+3); s_=__shfl(SARR,(BASE)+3); ry_lane<2>(s,lane,c_,s_); \
      c_=__shfl(CARR,(BASE)+4); s_=__shfl(SARR,(BASE)+4); ry_lane<1>(s,lane,c_,s_); \
      c_=__shfl(CARR,(BASE)+5); s_=__shfl(SARR,(BASE)+5); ry_lane<0>(s,lane,c_,s_); \
      c_=__shfl(CARR,(BASE)+6); s_=__shfl(SARR,(BASE)+6); ry_reg<3>(s,c_,s_);       \
      c_=__shfl(CARR,(BASE)+7); s_=__shfl(SARR,(BASE)+7); ry_reg<2>(s,c_,s_);       \
      c_=__shfl(CARR,(BASE)+8); s_=__shfl(SARR,(BASE)+8); ry_reg<1>(s,c_,s_);       \
      c_=__shfl(CARR,(BASE)+9); s_=__shfl(SARR,(BASE)+9); ry_reg<0>(s,c_,s_); }

__device__ __forceinline__ void async16(const void* g, void* l) {
    __builtin_amdgcn_global_load_lds(
        (const __attribute__((address_space(1))) void*)g,
        (__attribute__((address_space(3))) void*)l, 16, 0, 0);
}

// write one row (1024 f16 as wave registers) in fragment-major order.
// lane holds e = lane*16 + r; v0 = r 0..7, v1 = r 8..15.   [R9-verified]
__device__ __forceinline__ void store_frag_major(
    f16* base, int row, int lane, float4 v0, float4 v1)
{
    size_t idx0 = (size_t)(row >> 4) * 16384 + (size_t)(lane >> 1) * 512
                + (size_t)((row & 15) + ((lane & 1) * 2) * 16) * 8;
    *(float4*)((char*)base + idx0 * 2)       = v0;
    *(float4*)((char*)base + idx0 * 2 + 256) = v1;
}

// ---------------------------------------------------------------- KA  [R9-verified]
__global__ __launch_bounds__(256) void ka_prepare(
    const float* __restrict__ X, const float* __restrict__ Wpre,
    const float* __restrict__ bpre, const float* __restrict__ qp,
    f16* __restrict__ psi0F, f16* __restrict__ Armf, float* __restrict__ z,
    int* __restrict__ cnt, int B)
{
    const int tid = threadIdx.x, lane = tid & 63, wv = tid >> 6;

    {
        int idx = blockIdx.x * 256 + tid;
        if (idx < 8192 * NQ) z[idx] = 0.0f;
        else if (idx < 8192 * NQ + 128) cnt[idx - 8192 * NQ] = 0;
    }

    {
        int sample = blockIdx.x * 4 + wv;
        if (sample < B) {
            const float* xrow = X + (size_t)sample * 512;
            float4 x0 = ((const float4*)xrow)[lane];
            float4 x1 = ((const float4*)xrow)[64 + lane];
            float acc[NQ];
            #pragma unroll
            for (int q = 0; q < NQ; ++q) {
                const float* wr = Wpre + q * 512;
                float4 w0 = ((const float4*)wr)[lane];
                float4 w1 = ((const float4*)wr)[64 + lane];
                float a = x0.x * w0.x;
                a = fmaf(x0.y, w0.y, a); a = fmaf(x0.z, w0.z, a); a = fmaf(x0.w, w0.w, a);
                a = fmaf(x1.x, w1.x, a); a = fmaf(x1.y, w1.y, a);
                a = fmaf(x1.z, w1.z, a); a = fmaf(x1.w, w1.w, a);
                acc[q] = a;
            }
            #pragma unroll
            for (int q = 0; q < NQ; ++q) {
                float v = acc[q];
                #pragma unroll
                for (int d = 32; d >= 1; d >>= 1) v += __shfl_xor(v, d);
                acc[q] = v;
            }
            float pre = acc[0];
            #pragma unroll
            for (int q = 1; q < NQ; ++q) pre = (lane == q) ? acc[q] : pre;
            float c45 = 0.0f, s45 = 0.0f;
            if (lane < NQ) {
                float th = tanhf(pre + bpre[lane]) * 1.5707963267948966f;
                sincosf(0.5f * th + 0.7853981633974483f, &s45, &c45);
            }
            float lv = 1.0f;
            #pragma unroll
            for (int w = 0; w < 6; ++w) {
                float f0 = __shfl(c45, w), f1 = __shfl(s45, w);
                lv *= ((lane >> (5 - w)) & 1) ? f1 : f0;
            }
            float c6 = __shfl(c45, 6), s6 = __shfl(s45, 6);
            float c7 = __shfl(c45, 7), s7 = __shfl(s45, 7);
            float c8 = __shfl(c45, 8), s8 = __shfl(s45, 8);
            float c9 = __shfl(c45, 9), s9 = __shfl(s45, 9);
            float g01[4] = {c6 * c7, c6 * s7, s6 * c7, s6 * s7};
            float g23[4] = {c8 * c9, c8 * s9, s8 * c9, s8 * s9};
            union { f16 h[16]; float4 v[2]; } u;
            #pragma unroll
            for (int r = 0; r < NREG; ++r)
                u.h[r] = (f16)(lv * g01[r >> 2] * g23[r & 3]);
            store_frag_major(psi0F, sample, lane, u.v[0], u.v[1]);
        }
    }

    if (wv < 2) {
        int row = blockIdx.x * 2 + wv;
        if (row < DIM) {
            float cw = 1.0f, swn = 0.0f;
            if (lane < 60) {
                float s_, c_;
                sincosf(0.5f * qp[10 + lane], &s_, &c_);
                cw = c_; swn = -s_;
            }
            float s[NREG];
            int srcLane = row >> 4, srcReg = row & 15;
            #pragma unroll
            for (int r = 0; r < NREG; ++r)
                s[r] = (lane == srcLane && r == srcReg) ? 1.0f : 0.0f;
            for (int kk = 6; kk >= 1; --kk) {
                APPLY_RY_ALL(cw, swn, (kk - 1) * 10);
                perm_odd(s, lane);
                cnot_5_6(s, lane);
                cnot_reg<2, 1>(s);
                perm_even(s, lane);
                cnot_reg<3, 2>(s);
                cnot_reg<1, 0>(s);
            }
            union { f16 h[16]; float4 v[2]; } u;
            #pragma unroll
            for (int r = 0; r < NREG; ++r) u.h[r] = (f16)s[r];
            store_frag_major(Armf, row, lane, u.v[0], u.v[1]);
        }
    }
}

// ---------------------------------------------------------------- KB
// 64x128 (MxN) tile, BK=64, 1024 blocks (mB=blockIdx&127, nB=blockIdx>>7),
// double-buffered LDS (2 x 24KB -> 3 blocks/CU), one barrier per iter.
// Buffer layout: 24 runs of 1KB: A runs 0..7 (mt*2+kc), B runs 8..23 (ntf*2+kc).
__global__ __launch_bounds__(256, 3) void kb_gemm_measure(
    const f16* __restrict__ psi0F, const f16* __restrict__ Armf,
    const float* __restrict__ Wpost, const float* __restrict__ bpost,
    float* __restrict__ z, int* __restrict__ cnt, float* __restrict__ out)
{
    __shared__ __align__(16) char smem[49152];
    __shared__ int amLast;
    const int tid = threadIdx.x, lane = tid & 63, wv = tid >> 6;
    const int mB = blockIdx.x & 127, nB = blockIdx.x >> 7;
    const size_t tM = (size_t)mB * 64;
    const int wm = (wv >> 1) * 32, wn = (wv & 1) * 64;

    f32x4 acc[2][4] = {};

    // per-thread staging descriptors: 6 slots (1536 x 16B = 24KB)
    const char* gsrc[6]; int loff[6];
    #pragma unroll
    for (int p = 0; p < 6; ++p) {
        int s = p * 256 + tid;
        int run = s >> 6, i = s & 63;
        const char* base;
        if (run < 8) {
            int mt = run >> 1, kc = run & 1;
            base = (const char*)psi0F + ((size_t)(mB * 4 + mt)) * 32768 + (size_t)kc * 1024;
        } else {
            int rb = run - 8, ntf = rb >> 1, kc = rb & 1;
            base = (const char*)Armf + ((size_t)(nB * 8 + ntf)) * 32768 + (size_t)kc * 1024;
        }
        gsrc[p] = base + i * 16;
        loff[p] = s * 16;
    }

    // prefetch iter 0 into buffer 0
    #pragma unroll
    for (int p = 0; p < 6; ++p) async16(gsrc[p], smem + loff[p]);

    for (int it = 0; it < 16; ++it) {
        __syncthreads();  // buf[it&1] staged; prev compute reads of buf[(it+1)&1] done
        if (it < 15) {
            char* bn = smem + ((it & 1) ^ 1) * 24576;
            size_t go = (size_t)(it + 1) * 2048;  // 2 k-chunks per iter
            #pragma unroll
            for (int p = 0; p < 6; ++p) async16(gsrc[p] + go, bn + loff[p]);
        }
        const char* bc = smem + (it & 1) * 24576;
        #pragma unroll
        for (int kc = 0; kc < 2; ++kc) {
            f16x8 af[2], bf[4];
            #pragma unroll
            for (int i = 0; i < 2; ++i) {
                int mt = (wv >> 1) * 2 + i;
                af[i] = *(const f16x8*)(bc + (mt * 2 + kc) * 1024 + lane * 16);
            }
            #pragma unroll
            for (int j = 0; j < 4; ++j) {
                int ntf = (wv & 1) * 4 + j;
                bf[j] = *(const f16x8*)(bc + 8192 + (ntf * 2 + kc) * 1024 + lane * 16);
            }
            #pragma unroll
            for (int i = 0; i < 2; ++i)
                #pragma unroll
                for (int j = 0; j < 4; ++j)
                    acc[i][j] = __builtin_amdgcn_mfma_f32_16x16x32_f16(af[i], bf[j], acc[i][j], 0, 0, 0);
        }
    }

    // ---- fused +-square measurement epilogue (R6-verified mapping) ----
    // col n = nB*128 + wn + j*16 + (lane&15)
    const float sg0 = (nB & 4) ? -1.0f : 1.0f;  // wire0 <- n[9]
    const float sg1 = (nB & 2) ? -1.0f : 1.0f;  // wire1 <- n[8]
    const float sg2 = (nB & 1) ? -1.0f : 1.0f;  // wire2 <- n[7]
    const float sg3 = wn ? -1.0f : 1.0f;        // wire3 <- n[6]

    #pragma unroll
    for (int i = 0; i < 2; ++i) {
        #pragma unroll
        for (int t = 0; t < 4; ++t) {
            float p0 = acc[i][0][t] * acc[i][0][t];
            float p1 = acc[i][1][t] * acc[i][1][t];
            float p2 = acc[i][2][t] * acc[i][2][t];
            float p3 = acc[i][3][t] * acc[i][3][t];
            float t0  = (p0 + p1) + (p2 + p3);
            float tw5 = (p0 - p1) + (p2 - p3);  // wire5 <- n[4] = j&1
            float tw4 = (p0 + p1) - (p2 + p3);  // wire4 <- n[5] = j>>1
            // butterfly over lane bits 0..3 = n[0..3] -> wires 9,8,7,6
            float s1 = __shfl_xor(t0, 1);
            float Av = t0 + s1;
            float Bv = (lane & 1) ? s1 - t0 : t0 - s1;
            float sA = __shfl_xor(Av, 2), sB = __shfl_xor(Bv, 2);
            float AP = Av + sA;
            float AM = (lane & 2) ? sA - Av : Av - sA;
            float BP = Bv + sB;
            float sAP = __shfl_xor(AP, 4), sAM = __shfl_xor(AM, 4), sBP = __shfl_xor(BP, 4);
            float APP = AP + sAP;
            float APM = (lane & 4) ? sAP - AP : AP - sAP;
            float AMP = AM + sAM;
            float BPP = BP + sBP;
            float a1 = __shfl_xor(APP, 8), a2 = __shfl_xor(APM, 8);
            float a3 = __shfl_xor(AMP, 8), a4 = __shfl_xor(BPP, 8);
            float T0 = APP + a1;
            float S6 = (lane & 8) ? a1 - APP : APP - a1;
            float S7 = APM + a2;
            float S8 = AMP + a3;
            float S9 = BPP + a4;
            float T5 = tw5, T4 = tw4;
            T5 += __shfl_xor(T5, 1); T5 += __shfl_xor(T5, 2);
            T5 += __shfl_xor(T5, 4); T5 += __shfl_xor(T5, 8);
            T4 += __shfl_xor(T4, 1); T4 += __shfl_xor(T4, 2);
            T4 += __shfl_xor(T4, 4); T4 += __shfl_xor(T4, 8);
            if ((lane & 15) == 0) {
                int row = (int)tM + wm + i * 16 + (lane >> 4) * 4 + t;
                float* d = &z[(size_t)row * 10];
                atomicAdd(d + 0, sg0 * T0);
                atomicAdd(d + 1, sg1 * T0);
                atomicAdd(d + 2, sg2 * T0);
                atomicAdd(d + 3, sg3 * T0);
                atomicAdd(d + 4, T4);
                atomicAdd(d + 5, T5);
                atomicAdd(d + 6, S6);
                atomicAdd(d + 7, S7);
                atomicAdd(d + 8, S8);
                atomicAdd(d + 9, S9);
            }
        }
    }

    // ---- last-block-per-M-tile finalize (R7/R8-verified) ----
    __threadfence();
    __syncthreads();
    if (tid == 0) amLast = (atomicAdd(&cnt[mB], 1) == 7);
    __syncthreads();
    if (amLast) {
        for (int r = tid; r < 64; r += 256) {
            float* zp = &z[(tM + r) * 10];
            float o0 = bpost[0], o1 = bpost[1];
            #pragma unroll
            for (int w = 0; w < NQ; ++w) {
                float zw = atomicAdd(&zp[w], 0.0f);  // coherent read
                o0 = fmaf(zw, Wpost[w], o0);
                o1 = fmaf(zw, Wpost[NQ + w], o1);
            }
            out[(tM + r) * 2 + 0] = o0;
            out[(tM + r) * 2 + 1] = o1;
        }
    }
}

// ---------------------------------------------------------------- fallback (R1, verified)
template<int BC, int BT>
__device__ __forceinline__ void cnot_lane(float (&s)[NREG], int lane) {
    int src = ((lane >> BC) & 1) ? (lane ^ (1 << BT)) : lane;
    #pragma unroll
    for (int r = 0; r < NREG; ++r) s[r] = __shfl(s[r], src);
}

__global__ __launch_bounds__(256) void hybrid_head_fallback(
    const float* __restrict__ X, const float* __restrict__ Wpre,
    const float* __restrict__ bpre, const float* __restrict__ qp,
    const float* __restrict__ Wpost, const float* __restrict__ bpost,
    float* __restrict__ out, int B)
{
    const int lane = threadIdx.x & 63;
    const int wave = threadIdx.x >> 6;
    const int sample = blockIdx.x * 4 + wave;
    if (sample >= B) return;

    const float* xrow = X + (size_t)sample * 512;
    float4 x0 = ((const float4*)xrow)[lane];
    float4 x1 = ((const float4*)xrow)[64 + lane];
    float acc[NQ];
    #pragma unroll
    for (int q = 0; q < NQ; ++q) {
        const float* wr = Wpre + q * 512;
        float4 w0 = ((const float4*)wr)[lane];
        float4 w1 = ((const float4*)wr)[64 + lane];
        float a = x0.x * w0.x;
        a = fmaf(x0.y, w0.y, a); a = fmaf(x0.z, w0.z, a); a = fmaf(x0.w, w0.w, a);
        a = fmaf(x1.x, w1.x, a); a = fmaf(x1.y, w1.y, a);
        a = fmaf(x1.z, w1.z, a); a = fmaf(x1.w, w1.w, a);
        acc[q] = a;
    }
    #pragma unroll
    for (int q = 0; q < NQ; ++q) {
        float v = acc[q];
        #pragma unroll
        for (int d = 32; d >= 1; d >>= 1) v += __shfl_xor(v, d);
        acc[q] = v;
    }
    float pre = acc[0];
    #pragma unroll
    for (int q = 1; q < NQ; ++q) pre = (lane == q) ? acc[q] : pre;
    float cth = 1.0f, sth = 0.0f;
    if (lane < NQ) {
        float th = tanhf(pre + bpre[lane]) * 1.5707963267948966f;
        sincosf(0.5f * th, &sth, &cth);
    }
    float cw = 1.0f, sw = 0.0f;
    if (lane < 60) sincosf(0.5f * qp[10 + lane], &sw, &cw);

    float s[NREG];
    #pragma unroll
    for (int r = 0; r < NREG; ++r) s[r] = 0.03125f;
    APPLY_RY_ALL(cth, sth, 0);
    for (int k = 0; k < 6; ++k) {
        perm_even(s, lane);
        cnot_reg<3, 2>(s);
        cnot_reg<1, 0>(s);
        perm_odd(s, lane);
        cnot_5_6(s, lane);
        cnot_reg<2, 1>(s);
        APPLY_RY_ALL(cw, sw, k * 10);
    }
    float p[NREG], tot = 0.0f;
    #pragma unroll
    for (int r = 0; r < NREG; ++r) { p[r] = s[r] * s[r]; tot += p[r]; }
    float z[NQ];
    #pragma unroll
    for (int w = 0; w < 6; ++w) z[w] = ((lane >> (5 - w)) & 1) ? -tot : tot;
    z[6] = z[7] = z[8] = z[9] = 0.0f;
    #pragma unroll
    for (int r = 0; r < NREG; ++r) {
        z[6] += ((r >> 3) & 1) ? -p[r] : p[r];
        z[7] += ((r >> 2) & 1) ? -p[r] : p[r];
        z[8] += ((r >> 1) & 1) ? -p[r] : p[r];
        z[9] += ((r >> 0) & 1) ? -p[r] : p[r];
    }
    #pragma unroll
    for (int w = 0; w < NQ; ++w) {
        float v = z[w];
        #pragma unroll
        for (int d = 32; d >= 1; d >>= 1) v += __shfl_xor(v, d);
        z[w] = v;
    }
    if (lane < 2) {
        const float* wp = Wpost + lane * NQ;
        float o = bpost[lane];
        #pragma unroll
        for (int w = 0; w < NQ; ++w) o = fmaf(z[w], wp[w], o);
        out[(size_t)sample * 2 + lane] = o;
    }
}

// ---------------------------------------------------------------- launch
extern "C" void kernel_launch(void* const* d_in, const int* in_sizes, int n_in,
                              void* d_out, int out_size, void* d_ws, size_t ws_size,
                              hipStream_t stream) {
    const float* X     = (const float*)d_in[0];
    const float* Wpre  = (const float*)d_in[1];
    const float* bpre  = (const float*)d_in[2];
    const float* qp    = (const float*)d_in[3];
    const float* Wpost = (const float*)d_in[4];
    const float* bpost = (const float*)d_in[5];
    float* out = (float*)d_out;
    int B = in_sizes[0] / 512;  // 8192

    size_t psi0_b = (size_t)B * DIM * sizeof(f16);      // 16 MB
    size_t arm_b  = (size_t)DIM * DIM * sizeof(f16);    // 2 MB
    size_t z_b    = (size_t)B * NQ * sizeof(float);     // 320 KB
    size_t cnt_b  = 128 * sizeof(int);
    size_t need = psi0_b + arm_b + z_b + cnt_b;

    if (B != 8192 || ws_size < need) {
        hipLaunchKernelGGL(hybrid_head_fallback, dim3((B + 3) / 4), dim3(256), 0, stream,
                           X, Wpre, bpre, qp, Wpost, bpost, out, B);
        return;
    }

    char* ws = (char*)d_ws;
    f16*   psi0F = (f16*)ws;
    f16*   Armf  = (f16*)(ws + psi0_b);
    float* z     = (float*)(ws + psi0_b + arm_b);
    int*   cnt   = (int*)(ws + psi0_b + arm_b + z_b);

    hipLaunchKernelGGL(ka_prepare, dim3(2048), dim3(256), 0, stream,
                       X, Wpre, bpre, qp, psi0F, Armf, z, cnt, B);
    hipLaunchKernelGGL(kb_gemm_measure, dim3(1024), dim3(256), 0, stream,
                       psi0F, Armf, Wpost, bpost, z, cnt, out);
}

// Round 11
// 119.084 us; speedup vs baseline: 2.1608x; 2.0149x over previous
//
#include <hip/hip_runtime.h>
#include <math.h>

// BaseHybridHead, 3 stream-ordered kernels (R6 structure, tuned):
//  KA: pre-GEMM + rank-1 expand -> psi0 (8192x1024 f16, row-major); Arm rows
//      (1024x1024 f16); zero z[8192][10].          [R7-verified, 2048 blocks]
//  KB: MFMA GEMM psif = psi0 @ Arm^T, 128x128 tile, BK=64, XOR-swizzled LDS,
//      classic 2-barrier staged K-loop (the only structure that stayed <45us
//      across R2-R10), fused +-square measurement epilogue -> LDS combine ->
//      atomicAdd z.                                 [R6 staging + R7 epilogue]
//  KC: out = z @ Wpost^T + bpost.                   [R6-verified]

#define NQ   10
#define NREG 16
#define DIM  1024

typedef _Float16 f16;
typedef _Float16 f16x8 __attribute__((ext_vector_type(8)));
typedef float    f32x4 __attribute__((ext_vector_type(4)));

// ---------------------------------------------------------------- gate ops
template<int BB>
__device__ __forceinline__ void ry_lane(float (&s)[NREG], int lane, float c, float si) {
    float sgn = ((lane >> BB) & 1) ? si : -si;
    #pragma unroll
    for (int r = 0; r < NREG; ++r) {
        float o = __shfl_xor(s[r], 1 << BB);
        s[r] = fmaf(sgn, o, c * s[r]);
    }
}
template<int P>
__device__ __forceinline__ void ry_reg(float (&s)[NREG], float c, float si) {
    const int m = 1 << P;
    #pragma unroll
    for (int r = 0; r < NREG; ++r) {
        if ((r & m) == 0) {
            float a = s[r], b = s[r + m];
            s[r]     = fmaf(c, a, -si * b);
            s[r + m] = fmaf(si, a,  c * b);
        }
    }
}
__device__ __forceinline__ void cnot_5_6(float (&s)[NREG], int lane) {
    bool sel = (lane & 1) != 0;
    #pragma unroll
    for (int r = 0; r < 8; ++r) {
        float a = s[r], b = s[r + 8];
        s[r]     = sel ? b : a;
        s[r + 8] = sel ? a : b;
    }
}
template<int PC, int PT>
__device__ __forceinline__ void cnot_reg(float (&s)[NREG]) {
    #pragma unroll
    for (int r = 0; r < NREG; ++r) {
        if (((r >> PC) & 1) && !((r >> PT) & 1)) {
            float t = s[r];
            s[r] = s[r ^ (1 << PT)];
            s[r ^ (1 << PT)] = t;
        }
    }
}
__device__ __forceinline__ void perm_even(float (&s)[NREG], int lane) {
    int src = lane ^ (((((lane >> 5) & 1) << 4)) | ((((lane >> 3) & 1) << 2)) | (((lane >> 1) & 1)));
    #pragma unroll
    for (int r = 0; r < NREG; ++r) s[r] = __shfl(s[r], src);
}
__device__ __forceinline__ void perm_odd(float (&s)[NREG], int lane) {
    int src = lane ^ (((((lane >> 4) & 1) << 3)) | ((((lane >> 2) & 1) << 1)));
    #pragma unroll
    for (int r = 0; r < NREG; ++r) s[r] = __shfl(s[r], src);
}

#define APPLY_RY_ALL(CARR, SARR, BASE)                                        \
    { float c_, s_;                                                           \
      c_=__shfl(CARR,(BASE)+0); s_=__shfl(SARR,(BASE)+0); ry_lane<5>(s,lane,c_,s_); \
      c_=__shfl(CARR,(BASE)+1); s_=__shfl(SARR,(BASE)+1); ry_lane<4>(s,lane,c_,s_); \
      c_=__shfl(CARR,(BASE)+2); s_=__shfl(SARR,(BASE)+2); ry_lane<3>(s,lane,c_,s_); \
      c_=__shfl(CARR,(BASE)+3); s_=__shfl(SARR,(BASE)+3); ry_lane<2>(s,lane,c_,s_); \
      c_=__shfl(CARR,(BASE)+4); s_=__shfl(SARR,(BASE)+4); ry_lane<1>(s,lane,c_,s_); \
      c_=__shfl(CARR,(BASE)+5); s_=__shfl(SARR,(BASE)+5); ry_lane<0>(s,lane,c_,s_); \
      c_=__shfl(CARR,(BASE)+6); s_=__shfl(SARR,(BASE)+6); ry_reg<3>(s,c_,s_);       \
      c_=__shfl(CARR,(BASE)+7); s_=__shfl(SARR,(BASE)+7); ry_reg<2>(s,c_,s_);       \
      c_=__shfl(CARR,(BASE)+8); s_=__shfl(SARR,(BASE)+8); ry_reg<1>(s,c_,s_);       \
      c_=__shfl(CARR,(BASE)+9); s_=__shfl(SARR,(BASE)+9); ry_reg<0>(s,c_,s_); }

__device__ __forceinline__ void async16(const void* g, void* l) {
    __builtin_amdgcn_global_load_lds(
        (const __attribute__((address_space(1))) void*)g,
        (__attribute__((address_space(3))) void*)l, 16, 0, 0);
}

// ---------------------------------------------------------------- KA  [R7-verified]
// grid 2048 x 256: one sample per wave; blocks 0..511 also build 2 Arm rows each.
__global__ __launch_bounds__(256) void ka_prepare(
    const float* __restrict__ X, const float* __restrict__ Wpre,
    const float* __restrict__ bpre, const float* __restrict__ qp,
    f16* __restrict__ psi0, f16* __restrict__ Arm, float* __restrict__ z, int B)
{
    const int tid = threadIdx.x, lane = tid & 63, wv = tid >> 6;

    // ---- zero z accumulator (8192*10 floats; 2048x256 threads cover 1/thread)
    {
        int idx = blockIdx.x * 256 + tid;
        if (idx < 8192 * NQ) z[idx] = 0.0f;
    }

    // ---- psi0: one sample per wave
    {
        int sample = blockIdx.x * 4 + wv;
        if (sample < B) {
            const float* xrow = X + (size_t)sample * 512;
            float4 x0 = ((const float4*)xrow)[lane];
            float4 x1 = ((const float4*)xrow)[64 + lane];
            float acc[NQ];
            #pragma unroll
            for (int q = 0; q < NQ; ++q) {
                const float* wr = Wpre + q * 512;
                float4 w0 = ((const float4*)wr)[lane];
                float4 w1 = ((const float4*)wr)[64 + lane];
                float a = x0.x * w0.x;
                a = fmaf(x0.y, w0.y, a); a = fmaf(x0.z, w0.z, a); a = fmaf(x0.w, w0.w, a);
                a = fmaf(x1.x, w1.x, a); a = fmaf(x1.y, w1.y, a);
                a = fmaf(x1.z, w1.z, a); a = fmaf(x1.w, w1.w, a);
                acc[q] = a;
            }
            #pragma unroll
            for (int q = 0; q < NQ; ++q) {
                float v = acc[q];
                #pragma unroll
                for (int d = 32; d >= 1; d >>= 1) v += __shfl_xor(v, d);
                acc[q] = v;
            }
            float pre = acc[0];
            #pragma unroll
            for (int q = 1; q < NQ; ++q) pre = (lane == q) ? acc[q] : pre;
            float c45 = 0.0f, s45 = 0.0f;
            if (lane < NQ) {
                float th = tanhf(pre + bpre[lane]) * 1.5707963267948966f;
                sincosf(0.5f * th + 0.7853981633974483f, &s45, &c45);
            }
            float lv = 1.0f;
            #pragma unroll
            for (int w = 0; w < 6; ++w) {
                float f0 = __shfl(c45, w), f1 = __shfl(s45, w);
                lv *= ((lane >> (5 - w)) & 1) ? f1 : f0;
            }
            float c6 = __shfl(c45, 6), s6 = __shfl(s45, 6);
            float c7 = __shfl(c45, 7), s7 = __shfl(s45, 7);
            float c8 = __shfl(c45, 8), s8 = __shfl(s45, 8);
            float c9 = __shfl(c45, 9), s9 = __shfl(s45, 9);
            float g01[4] = {c6 * c7, c6 * s7, s6 * c7, s6 * s7};
            float g23[4] = {c8 * c9, c8 * s9, s8 * c9, s8 * s9};
            union { f16 h[16]; float4 v[2]; } u;
            #pragma unroll
            for (int r = 0; r < NREG; ++r)
                u.h[r] = (f16)(lv * g01[r >> 2] * g23[r & 3]);
            float4* dst = (float4*)((char*)psi0 + (size_t)sample * 2048 + lane * 32);
            dst[0] = u.v[0];
            dst[1] = u.v[1];
        }
    }

    // ---- Arm rows: blocks 0..511, waves 0,1 build row (blockIdx*2 + wv)
    if (wv < 2) {
        int row = blockIdx.x * 2 + wv;
        if (row < DIM) {
            float cw = 1.0f, swn = 0.0f;
            if (lane < 60) {
                float s_, c_;
                sincosf(0.5f * qp[10 + lane], &s_, &c_);
                cw = c_; swn = -s_;
            }
            float s[NREG];
            int srcLane = row >> 4, srcReg = row & 15;
            #pragma unroll
            for (int r = 0; r < NREG; ++r)
                s[r] = (lane == srcLane && r == srcReg) ? 1.0f : 0.0f;
            for (int kk = 6; kk >= 1; --kk) {
                APPLY_RY_ALL(cw, swn, (kk - 1) * 10);
                perm_odd(s, lane);
                cnot_5_6(s, lane);
                cnot_reg<2, 1>(s);
                perm_even(s, lane);
                cnot_reg<3, 2>(s);
                cnot_reg<1, 0>(s);
            }
            union { f16 h[16]; float4 v[2]; } u;
            #pragma unroll
            for (int r = 0; r < NREG; ++r) u.h[r] = (f16)s[r];
            float4* dst = (float4*)((char*)Arm + (size_t)row * 2048 + lane * 32);
            dst[0] = u.v[0];
            dst[1] = u.v[1];
        }
    }
}

// ---------------------------------------------------------------- KB
// 128x128 tile, BK=64, 512 blocks (mB=blockIdx&63 -> XCD affinity), classic
// 2-barrier staged K-loop with R6's XOR-swizzled LDS (conflict-free: measured
// 0 in R6; swizzle needs only rowA&7 == lane&7, which holds here too).
__global__ __launch_bounds__(256) void kb_gemm_measure(
    const f16* __restrict__ psi0, const f16* __restrict__ Arm,
    float* __restrict__ z)
{
    __shared__ __align__(16) char smem[32768];  // As 16K | Bs 16K ; reused as zbuf
    const int tid = threadIdx.x, lane = tid & 63, wv = tid >> 6;
    const int mB = blockIdx.x & 63, nB = blockIdx.x >> 6;
    const size_t tM = (size_t)mB * 128, tN = (size_t)nB * 128;
    f16* As = (f16*)smem;
    f16* Bs = (f16*)(smem + 16384);
    const int wm = (wv >> 1) * 64, wn = (wv & 1) * 64;

    f32x4 acc[4][4] = {};

    // staging: A/B each 1024 slots of 8 f16 -> 4 per thread, XOR-swizzled granule
    const f16* ga[4]; const f16* gb[4]; int ldso[4];
    #pragma unroll
    for (int p = 0; p < 4; ++p) {
        int slot = p * 256 + tid;
        int row = slot >> 3, gp = slot & 7, g = gp ^ (row & 7);
        ga[p] = psi0 + (tM + row) * 1024 + g * 8;
        gb[p] = Arm  + (tN + row) * 1024 + g * 8;
        ldso[p] = slot * 16;  // byte offset
    }

    for (int kt = 0; kt < 1024; kt += 64) {
        __syncthreads();  // protect LDS reuse from previous iter's reads
        #pragma unroll
        for (int p = 0; p < 4; ++p) async16(ga[p] + kt, (char*)As + ldso[p]);
        #pragma unroll
        for (int p = 0; p < 4; ++p) async16(gb[p] + kt, (char*)Bs + ldso[p]);
        __syncthreads();  // staging complete
        #pragma unroll
        for (int ks = 0; ks < 2; ++ks) {
            f16x8 af[4], bf[4];
            const int gpb = ks * 4 + (lane >> 4);
            const int gpx = gpb ^ (lane & 7);
            #pragma unroll
            for (int i = 0; i < 4; ++i) {
                int rowA = wm + i * 16 + (lane & 15);
                af[i] = *(const f16x8*)(As + rowA * 64 + gpx * 8);
            }
            #pragma unroll
            for (int j = 0; j < 4; ++j) {
                int rowB = wn + j * 16 + (lane & 15);
                bf[j] = *(const f16x8*)(Bs + rowB * 64 + gpx * 8);
            }
            #pragma unroll
            for (int i = 0; i < 4; ++i)
                #pragma unroll
                for (int j = 0; j < 4; ++j)
                    acc[i][j] = __builtin_amdgcn_mfma_f32_16x16x32_f16(af[i], bf[j], acc[i][j], 0, 0, 0);
        }
    }

    // ---- fused +-square measurement epilogue (R7-verified signs, R4-style zbuf) ----
    __syncthreads();  // done with As/Bs; reuse as zbuf[2][128][10] f32
    float* zbuf = (float*)smem;
    float* zb = zbuf + (wn ? 1280 : 0);
    const float sg0 = (nB & 4) ? -1.0f : 1.0f;  // wire0 <- n[9]
    const float sg1 = (nB & 2) ? -1.0f : 1.0f;  // wire1 <- n[8]
    const float sg2 = (nB & 1) ? -1.0f : 1.0f;  // wire2 <- n[7]
    const float sg3 = wn ? -1.0f : 1.0f;        // wire3 <- n[6]

    #pragma unroll
    for (int i = 0; i < 4; ++i) {
        #pragma unroll
        for (int t = 0; t < 4; ++t) {
            float p0 = acc[i][0][t] * acc[i][0][t];
            float p1 = acc[i][1][t] * acc[i][1][t];
            float p2 = acc[i][2][t] * acc[i][2][t];
            float p3 = acc[i][3][t] * acc[i][3][t];
            float t0  = (p0 + p1) + (p2 + p3);
            float tw5 = (p0 - p1) + (p2 - p3);  // wire5 <- n[4] = j&1
            float tw4 = (p0 + p1) - (p2 + p3);  // wire4 <- n[5] = j>>1
            // butterfly over lane bits 0..3 = n[0..3] -> wires 9,8,7,6
            float s1 = __shfl_xor(t0, 1);
            float Av = t0 + s1;
            float Bv = (lane & 1) ? s1 - t0 : t0 - s1;
            float sA = __shfl_xor(Av, 2), sB = __shfl_xor(Bv, 2);
            float AP = Av + sA;
            float AM = (lane & 2) ? sA - Av : Av - sA;
            float BP = Bv + sB;
            float sAP = __shfl_xor(AP, 4), sAM = __shfl_xor(AM, 4), sBP = __shfl_xor(BP, 4);
            float APP = AP + sAP;
            float APM = (lane & 4) ? sAP - AP : AP - sAP;
            float AMP = AM + sAM;
            float BPP = BP + sBP;
            float a1 = __shfl_xor(APP, 8), a2 = __shfl_xor(APM, 8);
            float a3 = __shfl_xor(AMP, 8), a4 = __shfl_xor(BPP, 8);
            float T0 = APP + a1;
            float S6 = (lane & 8) ? a1 - APP : APP - a1;
            float S7 = APM + a2;
            float S8 = AMP + a3;
            float S9 = BPP + a4;
            float T5 = tw5, T4 = tw4;
            T5 += __shfl_xor(T5, 1); T5 += __shfl_xor(T5, 2);
            T5 += __shfl_xor(T5, 4); T5 += __shfl_xor(T5, 8);
            T4 += __shfl_xor(T4, 1); T4 += __shfl_xor(T4, 2);
            T4 += __shfl_xor(T4, 4); T4 += __shfl_xor(T4, 8);
            if ((lane & 15) == 0) {
                int row = wm + i * 16 + (lane >> 4) * 4 + t;
                float* d = zb + row * 10;
                d[0] = sg0 * T0; d[1] = sg1 * T0; d[2] = sg2 * T0; d[3] = sg3 * T0;
                d[4] = T4; d[5] = T5;
                d[6] = S6; d[7] = S7; d[8] = S8; d[9] = S9;
            }
        }
    }
    __syncthreads();
    // combine col-halves, atomic-accumulate into z[tM+row][10]
    for (int idx = tid; idx < 1280; idx += 256) {
        float v = zbuf[idx] + zbuf[1280 + idx];
        int row = idx / 10, w = idx - row * 10;
        atomicAdd(&z[((size_t)tM + row) * 10 + w], v);
    }
}

// ---------------------------------------------------------------- KC  [R6-verified]
__global__ __launch_bounds__(256) void kc_post(
    const float* __restrict__ z, const float* __restrict__ Wpost,
    const float* __restrict__ bpost, float* __restrict__ out, int B)
{
    int gid = blockIdx.x * 256 + threadIdx.x;
    if (gid >= B) return;
    const float* zp = z + (size_t)gid * NQ;
    float o0 = bpost[0], o1 = bpost[1];
    #pragma unroll
    for (int w = 0; w < NQ; ++w) {
        float zw = zp[w];
        o0 = fmaf(zw, Wpost[w], o0);
        o1 = fmaf(zw, Wpost[NQ + w], o1);
    }
    out[(size_t)gid * 2 + 0] = o0;
    out[(size_t)gid * 2 + 1] = o1;
}

// ---------------------------------------------------------------- fallback (R1, verified)
template<int BC, int BT>
__device__ __forceinline__ void cnot_lane(float (&s)[NREG], int lane) {
    int src = ((lane >> BC) & 1) ? (lane ^ (1 << BT)) : lane;
    #pragma unroll
    for (int r = 0; r < NREG; ++r) s[r] = __shfl(s[r], src);
}

__global__ __launch_bounds__(256) void hybrid_head_fallback(
    const float* __restrict__ X, const float* __restrict__ Wpre,
    const float* __restrict__ bpre, const float* __restrict__ qp,
    const float* __restrict__ Wpost, const float* __restrict__ bpost,
    float* __restrict__ out, int B)
{
    const int lane = threadIdx.x & 63;
    const int wave = threadIdx.x >> 6;
    const int sample = blockIdx.x * 4 + wave;
    if (sample >= B) return;

    const float* xrow = X + (size_t)sample * 512;
    float4 x0 = ((const float4*)xrow)[lane];
    float4 x1 = ((const float4*)xrow)[64 + lane];
    float acc[NQ];
    #pragma unroll
    for (int q = 0; q < NQ; ++q) {
        const float* wr = Wpre + q * 512;
        float4 w0 = ((const float4*)wr)[lane];
        float4 w1 = ((const float4*)wr)[64 + lane];
        float a = x0.x * w0.x;
        a = fmaf(x0.y, w0.y, a); a = fmaf(x0.z, w0.z, a); a = fmaf(x0.w, w0.w, a);
        a = fmaf(x1.x, w1.x, a); a = fmaf(x1.y, w1.y, a);
        a = fmaf(x1.z, w1.z, a); a = fmaf(x1.w, w1.w, a);
        acc[q] = a;
    }
    #pragma unroll
    for (int q = 0; q < NQ; ++q) {
        float v = acc[q];
        #pragma unroll
        for (int d = 32; d >= 1; d >>= 1) v += __shfl_xor(v, d);
        acc[q] = v;
    }
    float pre = acc[0];
    #pragma unroll
    for (int q = 1; q < NQ; ++q) pre = (lane == q) ? acc[q] : pre;
    float cth = 1.0f, sth = 0.0f;
    if (lane < NQ) {
        float th = tanhf(pre + bpre[lane]) * 1.5707963267948966f;
        sincosf(0.5f * th, &sth, &cth);
    }
    float cw = 1.0f, sw = 0.0f;
    if (lane < 60) sincosf(0.5f * qp[10 + lane], &sw, &cw);

    float s[NREG];
    #pragma unroll
    for (int r = 0; r < NREG; ++r) s[r] = 0.03125f;
    APPLY_RY_ALL(cth, sth, 0);
    for (int k = 0; k < 6; ++k) {
        perm_even(s, lane);
        cnot_reg<3, 2>(s);
        cnot_reg<1, 0>(s);
        perm_odd(s, lane);
        cnot_5_6(s, lane);
        cnot_reg<2, 1>(s);
        APPLY_RY_ALL(cw, sw, k * 10);
    }
    float p[NREG], tot = 0.0f;
    #pragma unroll
    for (int r = 0; r < NREG; ++r) { p[r] = s[r] * s[r]; tot += p[r]; }
    float z[NQ];
    #pragma unroll
    for (int w = 0; w < 6; ++w) z[w] = ((lane >> (5 - w)) & 1) ? -tot : tot;
    z[6] = z[7] = z[8] = z[9] = 0.0f;
    #pragma unroll
    for (int r = 0; r < NREG; ++r) {
        z[6] += ((r >> 3) & 1) ? -p[r] : p[r];
        z[7] += ((r >> 2) & 1) ? -p[r] : p[r];
        z[8] += ((r >> 1) & 1) ? -p[r] : p[r];
        z[9] += ((r >> 0) & 1) ? -p[r] : p[r];
    }
    #pragma unroll
    for (int w = 0; w < NQ; ++w) {
        float v = z[w];
        #pragma unroll
        for (int d = 32; d >= 1; d >>= 1) v += __shfl_xor(v, d);
        z[w] = v;
    }
    if (lane < 2) {
        const float* wp = Wpost + lane * NQ;
        float o = bpost[lane];
        #pragma unroll
        for (int w = 0; w < NQ; ++w) o = fmaf(z[w], wp[w], o);
        out[(size_t)sample * 2 + lane] = o;
    }
}

// ---------------------------------------------------------------- launch
extern "C" void kernel_launch(void* const* d_in, const int* in_sizes, int n_in,
                              void* d_out, int out_size, void* d_ws, size_t ws_size,
                              hipStream_t stream) {
    const float* X     = (const float*)d_in[0];
    const float* Wpre  = (const float*)d_in[1];
    const float* bpre  = (const float*)d_in[2];
    const float* qp    = (const float*)d_in[3];
    const float* Wpost = (const float*)d_in[4];
    const float* bpost = (const float*)d_in[5];
    float* out = (float*)d_out;
    int B = in_sizes[0] / 512;  // 8192

    size_t psi0_b = (size_t)B * DIM * sizeof(f16);      // 16 MB
    size_t arm_b  = (size_t)DIM * DIM * sizeof(f16);    // 2 MB
    size_t z_b    = (size_t)B * NQ * sizeof(float);     // 320 KB
    size_t need = psi0_b + arm_b + z_b;

    if (B != 8192 || ws_size < need) {
        hipLaunchKernelGGL(hybrid_head_fallback, dim3((B + 3) / 4), dim3(256), 0, stream,
                           X, Wpre, bpre, qp, Wpost, bpost, out, B);
        return;
    }

    char* ws = (char*)d_ws;
    f16*   psi0 = (f16*)ws;
    f16*   Arm  = (f16*)(ws + psi0_b);
    float* z    = (float*)(ws + psi0_b + arm_b);

    hipLaunchKernelGGL(ka_prepare, dim3(2048), dim3(256), 0, stream,
                       X, Wpre, bpre, qp, psi0, Arm, z, B);
    hipLaunchKernelGGL(kb_gemm_measure, dim3(512), dim3(256), 0, stream,
                       psi0, Arm, z);
    hipLaunchKernelGGL(kc_post, dim3(32), dim3(256), 0, stream,
                       z, Wpost, bpost, out, B);
}